// Round 13
// baseline (379.121 us; speedup 1.0000x reference)
//
#include <hip/hip_runtime.h>
#include <hip/hip_bf16.h>

// Problem constants
#define Lc   2048
#define Dc   512
#define Hc   8
#define DKc  64
#define Bc   2
#define NSPLIT 4
#define BHLc (Bc*Hc*Lc)

typedef __attribute__((ext_vector_type(8))) short bf16x8;
typedef __attribute__((ext_vector_type(4))) float f32x4;
typedef __attribute__((ext_vector_type(4))) int   i32x4;
typedef unsigned short u16;

#define MFMA16(a, b, c) __builtin_amdgcn_mfma_f32_16x16x32_bf16((a), (b), (c), 0, 0, 0)

__device__ __forceinline__ u16 f2bf(float x) {
    union { float f; unsigned u; } v; v.f = x;
    unsigned r = v.u + 0x7FFFu + ((v.u >> 16) & 1u);   // RNE
    return (u16)(r >> 16);
}
__device__ __forceinline__ float bf2f(u16 x) {
    union { unsigned u; float f; } v; v.u = ((unsigned)x) << 16; return v.f;
}

union U16x8 { u16 us[8]; i32x4 v; };

// ---------------------------------------------------------------------------
// Stage a 64x64 fp32 tile -> bf16 LDS [row][k], XOR-swizzled 16B groups
// ---------------------------------------------------------------------------
template<int TRANS>
__device__ __forceinline__ void stage_tile(u16* sDst, const float* __restrict__ src,
                                           int r0, int k0, int ld, int t)
{
    if (!TRANS) {
        const int row = t >> 2, q = t & 3;
        const float* s = src + (size_t)(r0 + row) * ld + k0 + q * 16;
        float4 f0 = ((const float4*)s)[0];
        float4 f1 = ((const float4*)s)[1];
        float4 f2 = ((const float4*)s)[2];
        float4 f3 = ((const float4*)s)[3];
        U16x8 a, b;
        a.us[0]=f2bf(f0.x); a.us[1]=f2bf(f0.y); a.us[2]=f2bf(f0.z); a.us[3]=f2bf(f0.w);
        a.us[4]=f2bf(f1.x); a.us[5]=f2bf(f1.y); a.us[6]=f2bf(f1.z); a.us[7]=f2bf(f1.w);
        b.us[0]=f2bf(f2.x); b.us[1]=f2bf(f2.y); b.us[2]=f2bf(f2.z); b.us[3]=f2bf(f2.w);
        b.us[4]=f2bf(f3.x); b.us[5]=f2bf(f3.y); b.us[6]=f2bf(f3.z); b.us[7]=f2bf(f3.w);
        const int r7 = row & 7, base = row * 64;
        *(i32x4*)&sDst[base + (((q*2)     ^ r7) << 3)] = a.v;
        *(i32x4*)&sDst[base + (((q*2 + 1) ^ r7) << 3)] = b.v;
    } else {
        const int qq = t & 31, mg = t >> 5;
        const float* s0 = src + (size_t)(k0 + 2*qq) * ld + r0 + mg*8;
        const float* s1 = s0 + ld;
        float4 x0 = ((const float4*)s0)[0], x1 = ((const float4*)s0)[1];
        float4 y0 = ((const float4*)s1)[0], y1 = ((const float4*)s1)[1];
        float e0[8] = {x0.x,x0.y,x0.z,x0.w,x1.x,x1.y,x1.z,x1.w};
        float e1[8] = {y0.x,y0.y,y0.z,y0.w,y1.x,y1.y,y1.z,y1.w};
        unsigned* d32 = (unsigned*)sDst;
        const int g = qq >> 2, off = qq & 3;
#pragma unroll
        for (int e = 0; e < 8; ++e) {
            const int m = mg*8 + e;
            unsigned pk = (unsigned)f2bf(e0[e]) | ((unsigned)f2bf(e1[e]) << 16);
            d32[m*32 + ((g ^ (m & 7)) << 2) + off] = pk;
        }
    }
}

// ---------------------------------------------------------------------------
// GEMM core (device fn; LDS passed in). ABF=1: A already bf16 row-major.
// ---------------------------------------------------------------------------
template<int AT, int WT, int OUTMODE, int DUAL, int HASBIAS, int ADDSRC, int ABF>
__device__ __forceinline__
void gemm_core(u16* sA, u16* sB, int m0, int n0,
               const float* __restrict__ A, const float* __restrict__ W,
               const float* __restrict__ b1, const float* __restrict__ b2,
               const float* __restrict__ add, void* __restrict__ o1v,
               void* __restrict__ o2v, int ldA, int t)
{
    const int lane = t & 63, w = t >> 6;
    const int l15 = lane & 15, lg = lane >> 4;
    const int wm = w >> 1, wn = w & 1;

    f32x4 acc[2][2] = {};

    for (int k0 = 0; k0 < 512; k0 += 64) {
        __syncthreads();
        if (ABF) {
            const u16* A16 = (const u16*)A;
            const int row = t >> 2, q = t & 3;
            const u16* s = A16 + (size_t)(m0 + row) * 512 + k0 + q*16;
            i32x4 v0 = ((const i32x4*)s)[0];
            i32x4 v1 = ((const i32x4*)s)[1];
            const int r7 = row & 7, base = row * 64;
            *(i32x4*)&sA[base + (((q*2)     ^ r7) << 3)] = v0;
            *(i32x4*)&sA[base + (((q*2 + 1) ^ r7) << 3)] = v1;
        } else {
            stage_tile<AT>(sA, A, m0, k0, AT ? ldA : 512, t);
        }
        stage_tile<WT ? 0 : 1>(sB, W, n0, k0, 512, t);
        __syncthreads();
        const int l7 = l15 & 7;
#pragma unroll
        for (int kh = 0; kh < 2; ++kh) {
            bf16x8 av[2], bv[2];
#pragma unroll
            for (int f = 0; f < 2; ++f) {
                const int ra = wm*32 + f*16 + l15;
                av[f] = *(const bf16x8*)&sA[ra*64 + (((kh*4 + lg) ^ l7) << 3)];
                const int rb = wn*32 + f*16 + l15;
                bv[f] = *(const bf16x8*)&sB[rb*64 + (((kh*4 + lg) ^ l7) << 3)];
            }
#pragma unroll
            for (int fm = 0; fm < 2; ++fm)
#pragma unroll
                for (int fn = 0; fn < 2; ++fn)
                    acc[fm][fn] = MFMA16(av[fm], bv[fn], acc[fm][fn]);
        }
    }

#pragma unroll
    for (int fm = 0; fm < 2; ++fm)
#pragma unroll
    for (int fn = 0; fn < 2; ++fn) {
        const int colg = n0 + wn*32 + fn*16 + l15;
#pragma unroll
        for (int r = 0; r < 4; ++r) {
            const int row = m0 + wm*32 + fm*16 + lg*4 + r;
            float v = acc[fm][fn][r];
            if (OUTMODE == 0) {
                if (HASBIAS) v += b1[colg];
                if (ADDSRC)  v += add[(size_t)row*512 + colg];
                ((float*)o1v)[(size_t)row*512 + colg] = v;
            } else if (OUTMODE == 1) {
                if (HASBIAS) v += b1[colg];
                const int h = colg >> 6, dk = colg & 63;
                const int bb = row >> 11, ii = row & 2047;
                const size_t idx = (((size_t)(bb*Hc + h)*Lc + ii) << 6) + dk;
                ((u16*)o1v)[idx] = f2bf(v);
                if (DUAL)
                    ((u16*)o2v)[idx] = f2bf(acc[fm][fn][r] + b2[colg]);
            } else if (OUTMODE == 2) {
                const int h = row >> 6, dk = row & 63;
                const int bb = colg >> 11, ii = colg & 2047;
                ((u16*)o1v)[((size_t)(bb*Hc + h)*DKc + dk)*Lc + ii] = f2bf(v);
            } else {
                const int h = colg >> 6, dk = colg & 63;
                ((u16*)o1v)[(((size_t)h*Lc + row) << 6) + dk] = f2bf(v);
            }
        }
    }
}

// ---------------------------------------------------------------------------
// Tri-output core: qc = E@Wq + cb, qp = E@Wq + pb, k = E@Wke.
// ---------------------------------------------------------------------------
__device__ __forceinline__
void qkp_core(u16* sA, u16* sB1, u16* sB2, int m0, int n0,
              const float* __restrict__ E, const float* __restrict__ Wq,
              const float* __restrict__ Wke, const float* __restrict__ cb,
              const float* __restrict__ pb, u16* __restrict__ qcB,
              u16* __restrict__ qpB, u16* __restrict__ kB, int t)
{
    const int lane = t & 63, w = t >> 6;
    const int l15 = lane & 15, lg = lane >> 4;
    const int wm = w >> 1, wn = w & 1;

    f32x4 acc1[2][2] = {};
    f32x4 acc2[2][2] = {};

    for (int k0 = 0; k0 < 512; k0 += 64) {
        __syncthreads();
        stage_tile<0>(sA,  E,   m0, k0, 512, t);
        stage_tile<1>(sB1, Wq,  n0, k0, 512, t);
        stage_tile<1>(sB2, Wke, n0, k0, 512, t);
        __syncthreads();
        const int l7 = l15 & 7;
#pragma unroll
        for (int kh = 0; kh < 2; ++kh) {
            bf16x8 av[2], b1v[2], b2v[2];
#pragma unroll
            for (int f = 0; f < 2; ++f) {
                const int ra = wm*32 + f*16 + l15;
                av[f]  = *(const bf16x8*)&sA [ra*64 + (((kh*4 + lg) ^ l7) << 3)];
                const int rb = wn*32 + f*16 + l15;
                b1v[f] = *(const bf16x8*)&sB1[rb*64 + (((kh*4 + lg) ^ l7) << 3)];
                b2v[f] = *(const bf16x8*)&sB2[rb*64 + (((kh*4 + lg) ^ l7) << 3)];
            }
#pragma unroll
            for (int fm = 0; fm < 2; ++fm)
#pragma unroll
                for (int fn = 0; fn < 2; ++fn) {
                    acc1[fm][fn] = MFMA16(av[fm], b1v[fn], acc1[fm][fn]);
                    acc2[fm][fn] = MFMA16(av[fm], b2v[fn], acc2[fm][fn]);
                }
        }
    }

#pragma unroll
    for (int fm = 0; fm < 2; ++fm)
#pragma unroll
    for (int fn = 0; fn < 2; ++fn) {
        const int colg = n0 + wn*32 + fn*16 + l15;
        const int h = colg >> 6, dk = colg & 63;
#pragma unroll
        for (int r = 0; r < 4; ++r) {
            const int row = m0 + wm*32 + fm*16 + lg*4 + r;
            const int bb = row >> 11, ii = row & 2047;
            const size_t idx = (((size_t)(bb*Hc + h)*Lc + ii) << 6) + dk;
            qcB[idx] = f2bf(acc1[fm][fn][r] + cb[colg]);
            qpB[idx] = f2bf(acc1[fm][fn][r] + pb[colg]);
            kB[idx]  = f2bf(acc2[fm][fn][r]);
        }
    }
}

// ---------------------------------------------------------------------------
// Merged pre-GEMM dispatch: blocks [0,512) qc/qp/k tri-GEMM,
// [512,1024) V^T, [1024,1280) QRT. One 24KB LDS arena shared by all roles.
// ---------------------------------------------------------------------------
__global__ __launch_bounds__(256)
void pre_gemms(const float* __restrict__ E, const float* __restrict__ Wq,
               const float* __restrict__ Wke, const float* __restrict__ cb,
               const float* __restrict__ pb, const float* __restrict__ Wv,
               const float* __restrict__ Ev, const float* __restrict__ R,
               const float* __restrict__ Wkr,
               u16* __restrict__ qcB, u16* __restrict__ qpB, u16* __restrict__ kB,
               u16* __restrict__ vtB, u16* __restrict__ qrtB)
{
    __shared__ __align__(16) u16 smem[3*64*64];
    const int bid = blockIdx.x;
    const int t = threadIdx.x;
    if (bid < 512) {
        qkp_core(smem, smem + 4096, smem + 8192, (bid & 63) * 64, (bid >> 6) * 64,
                 E, Wq, Wke, cb, pb, qcB, qpB, kB, t);
    } else if (bid < 1024) {
        const int b2 = bid - 512;
        gemm_core<1,1,2,0,0,0,0>(smem, smem + 4096, (b2 & 7) * 64, (b2 >> 3) * 64,
                 Wv, Ev, nullptr, nullptr, nullptr, (void*)vtB, nullptr, 512, t);
    } else {
        const int b3 = bid - 1024;
        gemm_core<1,1,3,0,0,0,0>(smem, smem + 4096, (b3 & 31) * 64, (b3 >> 5) * 64,
                 R, Wkr, nullptr, nullptr, nullptr, (void*)qrtB, nullptr, 2048, t);
    }
}

// ---------------------------------------------------------------------------
// Standalone GEMM wrapper (used for the output projection, ABF path).
// ---------------------------------------------------------------------------
template<int AT, int WT, int OUTMODE, int DUAL, int HASBIAS, int ADDSRC, int ABF = 0>
__global__ __launch_bounds__(256)
void gemm_mfma(const float* __restrict__ A, const float* __restrict__ W,
               const float* __restrict__ b1, const float* __restrict__ b2,
               const float* __restrict__ add, void* __restrict__ o1v,
               void* __restrict__ o2v, int ldA)
{
    __shared__ __align__(16) u16 sA[64*64];
    __shared__ __align__(16) u16 sB[64*64];
    gemm_core<AT,WT,OUTMODE,DUAL,HASBIAS,ADDSRC,ABF>(
        sA, sB, blockIdx.x * 64, blockIdx.y * 64,
        A, W, b1, b2, add, o1v, o2v, ldA, threadIdx.x);
}

// ---------------------------------------------------------------------------
// MFMA fused relative attention, j-split. Round-13: 128-row Q tile, 8 waves
// (512 thr), grid 1024. Staging per thread 8->5 slots; LDS 75,776 B -> 2
// blocks/CU = 16 waves/CU (was 12). Per-wave math identical to r10/r12;
// index bases: dBase = j0-i0-127 (==1 mod 16), band 192 rows, cb = cbl+7-w,
// P2 strip r11-style [16][68] f32 (store slot c = cbl*16+l15+blm-15).
// ---------------------------------------------------------------------------
__global__ __launch_bounds__(512, 4)
void attn_mfma(const u16* __restrict__ qc, const u16* __restrict__ qp,
               const u16* __restrict__ kk, const u16* __restrict__ vt,
               const u16* __restrict__ qrt, u16* __restrict__ Opart,
               float* __restrict__ mlbuf)
{
    __shared__ __align__(16) u16 sK[64*64];
    __shared__ __align__(16) u16 sV[64*64];
    __shared__ __align__(16) u16 sBand[192*64];
    __shared__ __align__(16) float sP2[8*1088];   // per-wave f32[16][68] U u16 P[16][64]

    // XCD swizzle: nwg=1024 (%8==0) -> orig = (bx&7)*128 + bx>>3 (bijective)
    const int orig = ((blockIdx.x & 7) << 7) | (blockIdx.x >> 3);
    const int it = orig & 15;
    const int sp = (orig >> 4) & (NSPLIT - 1);
    const int bh = orig >> 6;
    const int h = bh & 7, b = bh >> 3;
    const int i0 = it << 7;
    const int t = threadIdx.x;
    const int lane = t & 63, w = t >> 6;          // w in [0,8)
    const int l15 = lane & 15, lg = lane >> 4;

    float* p2w = sP2 + w * 1088;
    u16*   spw = (u16*)p2w;

    const size_t ho = (size_t)(b*Hc + h) * (Lc * DKc);
    const u16* qcH  = qc  + ho;
    const u16* qpH  = qp  + ho;
    const u16* kH   = kk  + ho;
    const u16* vtH  = vt  + ho;
    const u16* qrtH = qrt + (size_t)h * (Lc * DKc);

    const int rowA = i0 + w*16 + l15;
    const int rowB = (rowA + 1 < Lc) ? rowA + 1 : Lc - 1;
    bf16x8 qc0 = *(const bf16x8*)(qcH + (size_t)rowA*64 +      lg*8);
    bf16x8 qc1 = *(const bf16x8*)(qcH + (size_t)rowA*64 + 32 + lg*8);
    bf16x8 qa0 = *(const bf16x8*)(qpH + (size_t)rowA*64 +      lg*8);
    bf16x8 qa1 = *(const bf16x8*)(qpH + (size_t)rowA*64 + 32 + lg*8);
    bf16x8 qb0 = *(const bf16x8*)(qpH + (size_t)rowB*64 +      lg*8);
    bf16x8 qb1 = *(const bf16x8*)(qpH + (size_t)rowB*64 + 32 + lg*8);

    f32x4 oacc[4] = {};
    float mrow[4] = {-1e30f, -1e30f, -1e30f, -1e30f};
    float lsum[4] = {0.f, 0.f, 0.f, 0.f};

    for (int jq = 0; jq < 32/NSPLIT; ++jq) {
        const int jt = sp * (32/NSPLIT) + jq;
        const int j0 = jt << 6;
        const int dBase = j0 - i0 - 127;
        __syncthreads();
        // ---- stage K, V^T (512 slots each over 512 threads) ----
        {
            const int row = t >> 3, g = t & 7;
            const int sl = row*64 + ((g ^ (row & 7)) << 3);
            *(i32x4*)&sK[sl] = *(const i32x4*)(kH  + (size_t)(j0+row)*64 + g*8);
            *(i32x4*)&sV[sl] = *(const i32x4*)(vtH + (size_t)row*Lc + j0 + g*8);
        }
        // ---- stage Band (192 rows = 1536 slots over 512 threads) ----
#pragma unroll
        for (int p = 0; p < 3; ++p) {
            const int s = t + p*512, dd = s >> 3, g = s & 7;
            const int d = dBase + dd;
            const int m = (d <= 0) ? (d + Lc - 1) : ((d >= 2) ? (d - 2) : 0);
            *(i32x4*)&sBand[dd*64 + ((g ^ (dd & 7)) << 3)] =
                *(const i32x4*)(qrtH + (size_t)m*64 + g*8);
        }
        __syncthreads();

        // ---- qk scores ----
        __builtin_amdgcn_s_setprio(1);
        f32x4 sc[4];
#pragma unroll
        for (int nb = 0; nb < 4; ++nb) {
            const int row = nb*16 + l15;
            bf16x8 k0 = *(const bf16x8*)&sK[row*64 + ((( lg    ) ^ (row & 7)) << 3)];
            bf16x8 k1 = *(const bf16x8*)&sK[row*64 + (((lg + 4) ^ (row & 7)) << 3)];
            f32x4 z = {0.f, 0.f, 0.f, 0.f};
            z = MFMA16(qc0, k0, z);
            z = MFMA16(qc1, k1, z);
            sc[nb] = z;
        }

        // ---- P2 band GEMM: the 5 cb blocks this wave needs ----
#pragma unroll
        for (int cbl = 0; cbl < 5; ++cbl) {
            const int cb  = cbl + 7 - w;          // wave-uniform
            const int row = cb*16 + l15;          // sBand row (= dd)
            bf16x8 b0 = *(const bf16x8*)&sBand[row*64 + ((( lg    ) ^ (row & 7)) << 3)];
            bf16x8 b1 = *(const bf16x8*)&sBand[row*64 + (((lg + 4) ^ (row & 7)) << 3)];
            f32x4 z = {0.f, 0.f, 0.f, 0.f};
            if ((dBase + cb*16) >= 1) {
                z = MFMA16(qb0, b0, z);
                z = MFMA16(qb1, b1, z);
            } else {
                z = MFMA16(qa0, b0, z);
                z = MFMA16(qa1, b1, z);
            }
#pragma unroll
            for (int r = 0; r < 4; ++r) {
                const int blm = lg*4 + r;
                const int c = cbl*16 + l15 + blm - 15;
                if ((unsigned)c < 64u) p2w[blm*68 + c] = z[r];
            }
        }
        __builtin_amdgcn_s_setprio(0);
        __asm__ volatile("" ::: "memory");

        // ---- gather shift term ----
        float pm[4];
#pragma unroll
        for (int r = 0; r < 4; ++r) {
            const int blm = lg*4 + r;
            const int blg = w*16 + blm;
#pragma unroll
            for (int nb = 0; nb < 4; ++nb) {
                const int jl = nb*16 + l15;
                const int d  = dBase + jl - blg + 127;
                const float pv = p2w[blm*68 + jl];
                sc[nb][r] += (d == 1) ? 0.f : pv;
            }
            pm[r] = fmaxf(fmaxf(sc[0][r], sc[1][r]), fmaxf(sc[2][r], sc[3][r]));
        }

        // ---- softmax: defer-max fast path ----
        const float over = fmaxf(fmaxf(pm[0]-mrow[0], pm[1]-mrow[1]),
                                 fmaxf(pm[2]-mrow[2], pm[3]-mrow[3]));
        if (__all(over <= 8.0f)) {
#pragma unroll
            for (int r = 0; r < 4; ++r) {
                float p0 = __expf(sc[0][r] - mrow[r]);
                float p1 = __expf(sc[1][r] - mrow[r]);
                float p2 = __expf(sc[2][r] - mrow[r]);
                float p3 = __expf(sc[3][r] - mrow[r]);
                sc[0][r] = p0; sc[1][r] = p1; sc[2][r] = p2; sc[3][r] = p3;
                lsum[r] += p0 + p1 + p2 + p3;
            }
        } else {
            float fsc[4];
#pragma unroll
            for (int r = 0; r < 4; ++r) {
                float mx = pm[r];
                mx = fmaxf(mx, __shfl_xor(mx, 1, 64));
                mx = fmaxf(mx, __shfl_xor(mx, 2, 64));
                mx = fmaxf(mx, __shfl_xor(mx, 4, 64));
                mx = fmaxf(mx, __shfl_xor(mx, 8, 64));
                const float mnew = fmaxf(mrow[r], mx);
                const float fac  = __expf(mrow[r] - mnew);
                mrow[r] = mnew;
                float p0 = __expf(sc[0][r] - mnew);
                float p1 = __expf(sc[1][r] - mnew);
                float p2 = __expf(sc[2][r] - mnew);
                float p3 = __expf(sc[3][r] - mnew);
                sc[0][r] = p0; sc[1][r] = p1; sc[2][r] = p2; sc[3][r] = p3;
                lsum[r] = lsum[r] * fac + (p0 + p1 + p2 + p3);
                fsc[r] = fac;
            }
#pragma unroll
            for (int nb = 0; nb < 4; ++nb)
#pragma unroll
                for (int r = 0; r < 4; ++r)
                    oacc[nb][r] *= fsc[r];
        }
        __asm__ volatile("" ::: "memory");

        // ---- write P (bf16, swizzled; aliases P2 strip; wave-private) ----
#pragma unroll
        for (int r = 0; r < 4; ++r) {
            const int blm = lg*4 + r;
#pragma unroll
            for (int nb = 0; nb < 4; ++nb) {
                const int jl = nb*16 + l15;
                spw[blm*64 + (((jl >> 3) ^ (blm & 7)) << 3) + (jl & 7)] = f2bf(sc[nb][r]);
            }
        }
        __asm__ volatile("" ::: "memory");

        // ---- PV (V from LDS) ----
        __builtin_amdgcn_s_setprio(1);
        {
            bf16x8 pa0 = *(const bf16x8*)&spw[l15*64 + ((( lg    ) ^ (l15 & 7)) << 3)];
            bf16x8 pa1 = *(const bf16x8*)&spw[l15*64 + (((lg + 4) ^ (l15 & 7)) << 3)];
#pragma unroll
            for (int nb = 0; nb < 4; ++nb) {
                const int row = nb*16 + l15;
                bf16x8 v0 = *(const bf16x8*)&sV[row*64 + ((( lg    ) ^ (row & 7)) << 3)];
                bf16x8 v1 = *(const bf16x8*)&sV[row*64 + (((lg + 4) ^ (row & 7)) << 3)];
                oacc[nb] = MFMA16(pa0, v0, oacc[nb]);
                oacc[nb] = MFMA16(pa1, v1, oacc[nb]);
            }
        }
        __builtin_amdgcn_s_setprio(0);
    }

    // ---- epilogue: reduce l, store bf16 O partial + (m,l) ----
    u16* Op = Opart + (size_t)sp * (Bc*Hc*Lc*DKc) + ho;
#pragma unroll
    for (int r = 0; r < 4; ++r) {
        float ls = lsum[r];
        ls += __shfl_xor(ls, 1, 64);
        ls += __shfl_xor(ls, 2, 64);
        ls += __shfl_xor(ls, 4, 64);
        ls += __shfl_xor(ls, 8, 64);
        const int bl = w*16 + lg*4 + r;
#pragma unroll
        for (int nb = 0; nb < 4; ++nb)
            Op[(size_t)(i0 + bl)*64 + nb*16 + l15] = f2bf(oacc[nb][r]);
        if (l15 == 0) {
            const int rglob = (b*Hc + h)*Lc + i0 + bl;
            *(float2*)&mlbuf[((size_t)sp*BHLc + rglob)*2] = make_float2(mrow[r], ls);
        }
    }
}

// ---------------------------------------------------------------------------
// Combine NSPLIT bf16 partials -> bf16 Oh (in-place into split 0).
// ---------------------------------------------------------------------------
__global__ __launch_bounds__(256)
void attn_combine(const u16* __restrict__ Opart, const float* __restrict__ mlbuf,
                  u16* __restrict__ Oh)
{
    const int t = threadIdx.x;
    const int row = blockIdx.x * 64 + (t >> 2);
    const int q = t & 3;
    const size_t NQl = (size_t)Bc * Hc * Lc * DKc;

    float m[NSPLIT], l[NSPLIT];
#pragma unroll
    for (int s = 0; s < NSPLIT; ++s) {
        float2 ml = *(const float2*)&mlbuf[((size_t)s*BHLc + row)*2];
        m[s] = ml.x; l[s] = ml.y;
    }
    float M = fmaxf(fmaxf(m[0], m[1]), fmaxf(m[2], m[3]));
    float wgt[NSPLIT], wsum = 0.f;
#pragma unroll
    for (int s = 0; s < NSPLIT; ++s) { wgt[s] = __expf(m[s] - M); wsum += l[s]*wgt[s]; }
    const float inv = 1.f / wsum;

    float acc[16] = {};
#pragma unroll
    for (int s = 0; s < NSPLIT; ++s) {
        const i32x4* src = (const i32x4*)(Opart + (size_t)s*NQl + (size_t)row*64 + q*16);
        U16x8 a, bb; a.v = src[0]; bb.v = src[1];
#pragma unroll
        for (int e = 0; e < 8; ++e) {
            acc[e]   += wgt[s] * bf2f(a.us[e]);
            acc[8+e] += wgt[s] * bf2f(bb.us[e]);
        }
    }
    U16x8 o0, o1;
#pragma unroll
    for (int e = 0; e < 8; ++e) {
        o0.us[e] = f2bf(acc[e]   * inv);
        o1.us[e] = f2bf(acc[8+e] * inv);
    }
    i32x4* dst = (i32x4*)(Oh + (size_t)row*64 + q*16);
    dst[0] = o0.v; dst[1] = o1.v;
}

// ---------------------------------------------------------------------------
// LayerNorm (unchanged)
// ---------------------------------------------------------------------------
__global__ __launch_bounds__(256)
void ln_kernel(const float* __restrict__ yr, const float* __restrict__ g,
               const float* __restrict__ be, float* __restrict__ out)
{
    const int row = blockIdx.x;
    const int t   = threadIdx.x;
    const float2 v = *(const float2*)&yr[(size_t)row * 512 + t*2];
    float sum = v.x + v.y;
    float sq  = v.x*v.x + v.y*v.y;
#pragma unroll
    for (int off = 1; off < 64; off <<= 1) {
        sum += __shfl_xor(sum, off, 64);
        sq  += __shfl_xor(sq,  off, 64);
    }
    __shared__ float ssum[4], ssq[4];
    if ((t & 63) == 0) { ssum[t >> 6] = sum; ssq[t >> 6] = sq; }
    __syncthreads();
    sum = ssum[0] + ssum[1] + ssum[2] + ssum[3];
    sq  = ssq[0]  + ssq[1]  + ssq[2]  + ssq[3];
    const float mu   = sum * (1.f / 512.f);
    const float var  = sq * (1.f / 512.f) - mu * mu;
    const float rstd = rsqrtf(var + 1e-5f);
    float2 ov;
    ov.x = (v.x - mu) * rstd * g[t*2+0] + be[t*2+0];
    ov.y = (v.y - mu) * rstd * g[t*2+1] + be[t*2+1];
    *(float2*)&out[(size_t)row * 512 + t*2] = ov;
}

// ---------------------------------------------------------------------------
extern "C" void kernel_launch(void* const* d_in, const int* in_sizes, int n_in,
                              void* d_out, int out_size, void* d_ws, size_t ws_size,
                              hipStream_t stream)
{
    const float* E    = (const float*)d_in[0];
    const float* Ev   = (const float*)d_in[1];
    const float* R    = (const float*)d_in[2];
    const float* Wq   = (const float*)d_in[3];
    const float* Wke  = (const float*)d_in[4];
    const float* Wv   = (const float*)d_in[5];
    const float* Wkr  = (const float*)d_in[6];
    const float* cb   = (const float*)d_in[7];
    const float* pb   = (const float*)d_in[8];
    const float* Wo_w = (const float*)d_in[9];
    const float* Wo_b = (const float*)d_in[10];
    const float* ln_g = (const float*)d_in[11];
    const float* ln_b = (const float*)d_in[12];
    float* out = (float*)d_out;

    const size_t NQ = (size_t)Bc * Hc * Lc * DKc;   // 2,097,152
    const size_t NR = (size_t)Hc * Lc * DKc;        // 1,048,576
    const size_t need = (4*NQ + NR)*2 + (size_t)NSPLIT*NQ*2 + (size_t)NSPLIT*BHLc*2*4;
    if (ws_size < need) return;

    u16* qcB  = (u16*)d_ws;
    u16* qpB  = qcB + NQ;
    u16* kB   = qpB + NQ;
    u16* vtB  = kB  + NQ;
    u16* qrtB = vtB + NQ;
    u16* Opart = qrtB + NR;                         // NSPLIT * NQ u16
    float* mlbuf = (float*)(Opart + (size_t)NSPLIT*NQ);
    u16* Oh16 = Opart;                              // combine output aliases split 0
    float* yr = (float*)(Opart + NQ);               // aliases splits 1-2 (f32 NQ)

    dim3 blk(256);
    // merged pre-GEMMs: qc/qp/k (512 blk) + V^T (512 blk) + QRT (256 blk)
    pre_gemms<<<dim3(1280), blk, 0, stream>>>(E, Wq, Wke, cb, pb, Wv, Ev, R, Wkr,
                                              qcB, qpB, kB, vtB, qrtB);
    // fused MFMA attention, j-split: grid = B*H*NSPLIT*(L/128) = 1024, 512 thr
    attn_mfma<<<dim3(Bc*Hc*NSPLIT*(Lc/128)), dim3(512), 0, stream>>>(qcB, qpB, kB, vtB, qrtB, Opart, mlbuf);
    attn_combine<<<dim3(BHLc/64), blk, 0, stream>>>(Opart, mlbuf, Oh16);
    // y = Ev + Oh(bf16, flat 4096x512) @ Wo_w^T + Wo_b (fp32)
    gemm_mfma<0,1,0,0,1,1,1><<<dim3(64,8), blk, 0, stream>>>((const float*)Oh16, Wo_w, Wo_b, nullptr, Ev, yr, nullptr, 512);
    // layernorm
    ln_kernel<<<dim3(4096), blk, 0, stream>>>(yr, ln_g, ln_b, out);
}

// Round 14
// 162.688 us; speedup vs baseline: 2.3304x; 2.3304x over previous
//
#include <hip/hip_runtime.h>
#include <hip/hip_bf16.h>

// Problem constants
#define Lc   2048
#define Dc   512
#define Hc   8
#define DKc  64
#define Bc   2
#define NSPLIT 4
#define BHLc (Bc*Hc*Lc)

typedef __attribute__((ext_vector_type(8))) short bf16x8;
typedef __attribute__((ext_vector_type(4))) float f32x4;
typedef __attribute__((ext_vector_type(4))) int   i32x4;
typedef unsigned short u16;

#define MFMA16(a, b, c) __builtin_amdgcn_mfma_f32_16x16x32_bf16((a), (b), (c), 0, 0, 0)

__device__ __forceinline__ u16 f2bf(float x) {
    union { float f; unsigned u; } v; v.f = x;
    unsigned r = v.u + 0x7FFFu + ((v.u >> 16) & 1u);   // RNE
    return (u16)(r >> 16);
}
__device__ __forceinline__ float bf2f(u16 x) {
    union { unsigned u; float f; } v; v.u = ((unsigned)x) << 16; return v.f;
}

union U16x8 { u16 us[8]; i32x4 v; };

// ---------------------------------------------------------------------------
// Stage a 64x64 fp32 tile -> bf16 LDS [row][k], XOR-swizzled 16B groups
// ---------------------------------------------------------------------------
template<int TRANS>
__device__ __forceinline__ void stage_tile(u16* sDst, const float* __restrict__ src,
                                           int r0, int k0, int ld, int t)
{
    if (!TRANS) {
        const int row = t >> 2, q = t & 3;
        const float* s = src + (size_t)(r0 + row) * ld + k0 + q * 16;
        float4 f0 = ((const float4*)s)[0];
        float4 f1 = ((const float4*)s)[1];
        float4 f2 = ((const float4*)s)[2];
        float4 f3 = ((const float4*)s)[3];
        U16x8 a, b;
        a.us[0]=f2bf(f0.x); a.us[1]=f2bf(f0.y); a.us[2]=f2bf(f0.z); a.us[3]=f2bf(f0.w);
        a.us[4]=f2bf(f1.x); a.us[5]=f2bf(f1.y); a.us[6]=f2bf(f1.z); a.us[7]=f2bf(f1.w);
        b.us[0]=f2bf(f2.x); b.us[1]=f2bf(f2.y); b.us[2]=f2bf(f2.z); b.us[3]=f2bf(f2.w);
        b.us[4]=f2bf(f3.x); b.us[5]=f2bf(f3.y); b.us[6]=f2bf(f3.z); b.us[7]=f2bf(f3.w);
        const int r7 = row & 7, base = row * 64;
        *(i32x4*)&sDst[base + (((q*2)     ^ r7) << 3)] = a.v;
        *(i32x4*)&sDst[base + (((q*2 + 1) ^ r7) << 3)] = b.v;
    } else {
        const int qq = t & 31, mg = t >> 5;
        const float* s0 = src + (size_t)(k0 + 2*qq) * ld + r0 + mg*8;
        const float* s1 = s0 + ld;
        float4 x0 = ((const float4*)s0)[0], x1 = ((const float4*)s0)[1];
        float4 y0 = ((const float4*)s1)[0], y1 = ((const float4*)s1)[1];
        float e0[8] = {x0.x,x0.y,x0.z,x0.w,x1.x,x1.y,x1.z,x1.w};
        float e1[8] = {y0.x,y0.y,y0.z,y0.w,y1.x,y1.y,y1.z,y1.w};
        unsigned* d32 = (unsigned*)sDst;
        const int g = qq >> 2, off = qq & 3;
#pragma unroll
        for (int e = 0; e < 8; ++e) {
            const int m = mg*8 + e;
            unsigned pk = (unsigned)f2bf(e0[e]) | ((unsigned)f2bf(e1[e]) << 16);
            d32[m*32 + ((g ^ (m & 7)) << 2) + off] = pk;
        }
    }
}

// ---------------------------------------------------------------------------
// GEMM core (device fn; LDS passed in). ABF=1: A already bf16 row-major.
// ---------------------------------------------------------------------------
template<int AT, int WT, int OUTMODE, int DUAL, int HASBIAS, int ADDSRC, int ABF>
__device__ __forceinline__
void gemm_core(u16* sA, u16* sB, int m0, int n0,
               const float* __restrict__ A, const float* __restrict__ W,
               const float* __restrict__ b1, const float* __restrict__ b2,
               const float* __restrict__ add, void* __restrict__ o1v,
               void* __restrict__ o2v, int ldA, int t)
{
    const int lane = t & 63, w = t >> 6;
    const int l15 = lane & 15, lg = lane >> 4;
    const int wm = w >> 1, wn = w & 1;

    f32x4 acc[2][2] = {};

    for (int k0 = 0; k0 < 512; k0 += 64) {
        __syncthreads();
        if (ABF) {
            const u16* A16 = (const u16*)A;
            const int row = t >> 2, q = t & 3;
            const u16* s = A16 + (size_t)(m0 + row) * 512 + k0 + q*16;
            i32x4 v0 = ((const i32x4*)s)[0];
            i32x4 v1 = ((const i32x4*)s)[1];
            const int r7 = row & 7, base = row * 64;
            *(i32x4*)&sA[base + (((q*2)     ^ r7) << 3)] = v0;
            *(i32x4*)&sA[base + (((q*2 + 1) ^ r7) << 3)] = v1;
        } else {
            stage_tile<AT>(sA, A, m0, k0, AT ? ldA : 512, t);
        }
        stage_tile<WT ? 0 : 1>(sB, W, n0, k0, 512, t);
        __syncthreads();
        const int l7 = l15 & 7;
#pragma unroll
        for (int kh = 0; kh < 2; ++kh) {
            bf16x8 av[2], bv[2];
#pragma unroll
            for (int f = 0; f < 2; ++f) {
                const int ra = wm*32 + f*16 + l15;
                av[f] = *(const bf16x8*)&sA[ra*64 + (((kh*4 + lg) ^ l7) << 3)];
                const int rb = wn*32 + f*16 + l15;
                bv[f] = *(const bf16x8*)&sB[rb*64 + (((kh*4 + lg) ^ l7) << 3)];
            }
#pragma unroll
            for (int fm = 0; fm < 2; ++fm)
#pragma unroll
                for (int fn = 0; fn < 2; ++fn)
                    acc[fm][fn] = MFMA16(av[fm], bv[fn], acc[fm][fn]);
        }
    }

#pragma unroll
    for (int fm = 0; fm < 2; ++fm)
#pragma unroll
    for (int fn = 0; fn < 2; ++fn) {
        const int colg = n0 + wn*32 + fn*16 + l15;
#pragma unroll
        for (int r = 0; r < 4; ++r) {
            const int row = m0 + wm*32 + fm*16 + lg*4 + r;
            float v = acc[fm][fn][r];
            if (OUTMODE == 0) {
                if (HASBIAS) v += b1[colg];
                if (ADDSRC)  v += add[(size_t)row*512 + colg];
                ((float*)o1v)[(size_t)row*512 + colg] = v;
            } else if (OUTMODE == 1) {
                if (HASBIAS) v += b1[colg];
                const int h = colg >> 6, dk = colg & 63;
                const int bb = row >> 11, ii = row & 2047;
                const size_t idx = (((size_t)(bb*Hc + h)*Lc + ii) << 6) + dk;
                ((u16*)o1v)[idx] = f2bf(v);
                if (DUAL)
                    ((u16*)o2v)[idx] = f2bf(acc[fm][fn][r] + b2[colg]);
            } else if (OUTMODE == 2) {
                const int h = row >> 6, dk = row & 63;
                const int bb = colg >> 11, ii = colg & 2047;
                ((u16*)o1v)[((size_t)(bb*Hc + h)*DKc + dk)*Lc + ii] = f2bf(v);
            } else {
                const int h = colg >> 6, dk = colg & 63;
                ((u16*)o1v)[(((size_t)h*Lc + row) << 6) + dk] = f2bf(v);
            }
        }
    }
}

// ---------------------------------------------------------------------------
// Tri-output core: qc = E@Wq + cb, qp = E@Wq + pb, k = E@Wke.
// ---------------------------------------------------------------------------
__device__ __forceinline__
void qkp_core(u16* sA, u16* sB1, u16* sB2, int m0, int n0,
              const float* __restrict__ E, const float* __restrict__ Wq,
              const float* __restrict__ Wke, const float* __restrict__ cb,
              const float* __restrict__ pb, u16* __restrict__ qcB,
              u16* __restrict__ qpB, u16* __restrict__ kB, int t)
{
    const int lane = t & 63, w = t >> 6;
    const int l15 = lane & 15, lg = lane >> 4;
    const int wm = w >> 1, wn = w & 1;

    f32x4 acc1[2][2] = {};
    f32x4 acc2[2][2] = {};

    for (int k0 = 0; k0 < 512; k0 += 64) {
        __syncthreads();
        stage_tile<0>(sA,  E,   m0, k0, 512, t);
        stage_tile<1>(sB1, Wq,  n0, k0, 512, t);
        stage_tile<1>(sB2, Wke, n0, k0, 512, t);
        __syncthreads();
        const int l7 = l15 & 7;
#pragma unroll
        for (int kh = 0; kh < 2; ++kh) {
            bf16x8 av[2], b1v[2], b2v[2];
#pragma unroll
            for (int f = 0; f < 2; ++f) {
                const int ra = wm*32 + f*16 + l15;
                av[f]  = *(const bf16x8*)&sA [ra*64 + (((kh*4 + lg) ^ l7) << 3)];
                const int rb = wn*32 + f*16 + l15;
                b1v[f] = *(const bf16x8*)&sB1[rb*64 + (((kh*4 + lg) ^ l7) << 3)];
                b2v[f] = *(const bf16x8*)&sB2[rb*64 + (((kh*4 + lg) ^ l7) << 3)];
            }
#pragma unroll
            for (int fm = 0; fm < 2; ++fm)
#pragma unroll
                for (int fn = 0; fn < 2; ++fn) {
                    acc1[fm][fn] = MFMA16(av[fm], b1v[fn], acc1[fm][fn]);
                    acc2[fm][fn] = MFMA16(av[fm], b2v[fn], acc2[fm][fn]);
                }
        }
    }

#pragma unroll
    for (int fm = 0; fm < 2; ++fm)
#pragma unroll
    for (int fn = 0; fn < 2; ++fn) {
        const int colg = n0 + wn*32 + fn*16 + l15;
        const int h = colg >> 6, dk = colg & 63;
#pragma unroll
        for (int r = 0; r < 4; ++r) {
            const int row = m0 + wm*32 + fm*16 + lg*4 + r;
            const int bb = row >> 11, ii = row & 2047;
            const size_t idx = (((size_t)(bb*Hc + h)*Lc + ii) << 6) + dk;
            qcB[idx] = f2bf(acc1[fm][fn][r] + cb[colg]);
            qpB[idx] = f2bf(acc1[fm][fn][r] + pb[colg]);
            kB[idx]  = f2bf(acc2[fm][fn][r]);
        }
    }
}

// ---------------------------------------------------------------------------
// Merged pre-GEMM dispatch: blocks [0,512) qc/qp/k tri-GEMM,
// [512,1024) V^T, [1024,1280) QRT. One 24KB LDS arena shared by all roles.
// ---------------------------------------------------------------------------
__global__ __launch_bounds__(256)
void pre_gemms(const float* __restrict__ E, const float* __restrict__ Wq,
               const float* __restrict__ Wke, const float* __restrict__ cb,
               const float* __restrict__ pb, const float* __restrict__ Wv,
               const float* __restrict__ Ev, const float* __restrict__ R,
               const float* __restrict__ Wkr,
               u16* __restrict__ qcB, u16* __restrict__ qpB, u16* __restrict__ kB,
               u16* __restrict__ vtB, u16* __restrict__ qrtB)
{
    __shared__ __align__(16) u16 smem[3*64*64];
    const int bid = blockIdx.x;
    const int t = threadIdx.x;
    if (bid < 512) {
        qkp_core(smem, smem + 4096, smem + 8192, (bid & 63) * 64, (bid >> 6) * 64,
                 E, Wq, Wke, cb, pb, qcB, qpB, kB, t);
    } else if (bid < 1024) {
        const int b2 = bid - 512;
        gemm_core<1,1,2,0,0,0,0>(smem, smem + 4096, (b2 & 7) * 64, (b2 >> 3) * 64,
                 Wv, Ev, nullptr, nullptr, nullptr, (void*)vtB, nullptr, 512, t);
    } else {
        const int b3 = bid - 1024;
        gemm_core<1,1,3,0,0,0,0>(smem, smem + 4096, (b3 & 31) * 64, (b3 >> 5) * 64,
                 R, Wkr, nullptr, nullptr, nullptr, (void*)qrtB, nullptr, 2048, t);
    }
}

// ---------------------------------------------------------------------------
// Standalone GEMM wrapper (used for the output projection, ABF path).
// ---------------------------------------------------------------------------
template<int AT, int WT, int OUTMODE, int DUAL, int HASBIAS, int ADDSRC, int ABF = 0>
__global__ __launch_bounds__(256)
void gemm_mfma(const float* __restrict__ A, const float* __restrict__ W,
               const float* __restrict__ b1, const float* __restrict__ b2,
               const float* __restrict__ add, void* __restrict__ o1v,
               void* __restrict__ o2v, int ldA)
{
    __shared__ __align__(16) u16 sA[64*64];
    __shared__ __align__(16) u16 sB[64*64];
    gemm_core<AT,WT,OUTMODE,DUAL,HASBIAS,ADDSRC,ABF>(
        sA, sB, blockIdx.x * 64, blockIdx.y * 64,
        A, W, b1, b2, add, o1v, o2v, ldA, threadIdx.x);
}

// ---------------------------------------------------------------------------
// MFMA fused relative attention, j-split. Round-14 = r13 structure with the
// VGPR pin fixed: __launch_bounds__(512, 2) -> 128-VGPR budget, no spills
// (r13's (512,4) forced VGPR=64 -> 518 MB scratch spill traffic).
// 128-row Q tile, 8 waves, grid 1024; LDS 75,776 B -> 2 blocks/CU.
// ---------------------------------------------------------------------------
__global__ __launch_bounds__(512, 2)
void attn_mfma(const u16* __restrict__ qc, const u16* __restrict__ qp,
               const u16* __restrict__ kk, const u16* __restrict__ vt,
               const u16* __restrict__ qrt, u16* __restrict__ Opart,
               float* __restrict__ mlbuf)
{
    __shared__ __align__(16) u16 sK[64*64];
    __shared__ __align__(16) u16 sV[64*64];
    __shared__ __align__(16) u16 sBand[192*64];
    __shared__ __align__(16) float sP2[8*1088];   // per-wave f32[16][68] U u16 P[16][64]

    // XCD swizzle: nwg=1024 (%8==0) -> orig = (bx&7)*128 + bx>>3 (bijective)
    const int orig = ((blockIdx.x & 7) << 7) | (blockIdx.x >> 3);
    const int it = orig & 15;
    const int sp = (orig >> 4) & (NSPLIT - 1);
    const int bh = orig >> 6;
    const int h = bh & 7, b = bh >> 3;
    const int i0 = it << 7;
    const int t = threadIdx.x;
    const int lane = t & 63, w = t >> 6;          // w in [0,8)
    const int l15 = lane & 15, lg = lane >> 4;

    float* p2w = sP2 + w * 1088;
    u16*   spw = (u16*)p2w;

    const size_t ho = (size_t)(b*Hc + h) * (Lc * DKc);
    const u16* qcH  = qc  + ho;
    const u16* qpH  = qp  + ho;
    const u16* kH   = kk  + ho;
    const u16* vtH  = vt  + ho;
    const u16* qrtH = qrt + (size_t)h * (Lc * DKc);

    const int rowA = i0 + w*16 + l15;
    const int rowB = (rowA + 1 < Lc) ? rowA + 1 : Lc - 1;
    bf16x8 qc0 = *(const bf16x8*)(qcH + (size_t)rowA*64 +      lg*8);
    bf16x8 qc1 = *(const bf16x8*)(qcH + (size_t)rowA*64 + 32 + lg*8);
    bf16x8 qa0 = *(const bf16x8*)(qpH + (size_t)rowA*64 +      lg*8);
    bf16x8 qa1 = *(const bf16x8*)(qpH + (size_t)rowA*64 + 32 + lg*8);
    bf16x8 qb0 = *(const bf16x8*)(qpH + (size_t)rowB*64 +      lg*8);
    bf16x8 qb1 = *(const bf16x8*)(qpH + (size_t)rowB*64 + 32 + lg*8);

    f32x4 oacc[4] = {};
    float mrow[4] = {-1e30f, -1e30f, -1e30f, -1e30f};
    float lsum[4] = {0.f, 0.f, 0.f, 0.f};

    for (int jq = 0; jq < 32/NSPLIT; ++jq) {
        const int jt = sp * (32/NSPLIT) + jq;
        const int j0 = jt << 6;
        const int dBase = j0 - i0 - 127;
        __syncthreads();
        // ---- stage K, V^T (512 slots each over 512 threads) ----
        {
            const int row = t >> 3, g = t & 7;
            const int sl = row*64 + ((g ^ (row & 7)) << 3);
            *(i32x4*)&sK[sl] = *(const i32x4*)(kH  + (size_t)(j0+row)*64 + g*8);
            *(i32x4*)&sV[sl] = *(const i32x4*)(vtH + (size_t)row*Lc + j0 + g*8);
        }
        // ---- stage Band (192 rows = 1536 slots over 512 threads) ----
#pragma unroll
        for (int p = 0; p < 3; ++p) {
            const int s = t + p*512, dd = s >> 3, g = s & 7;
            const int d = dBase + dd;
            const int m = (d <= 0) ? (d + Lc - 1) : ((d >= 2) ? (d - 2) : 0);
            *(i32x4*)&sBand[dd*64 + ((g ^ (dd & 7)) << 3)] =
                *(const i32x4*)(qrtH + (size_t)m*64 + g*8);
        }
        __syncthreads();

        // ---- qk scores ----
        __builtin_amdgcn_s_setprio(1);
        f32x4 sc[4];
#pragma unroll
        for (int nb = 0; nb < 4; ++nb) {
            const int row = nb*16 + l15;
            bf16x8 k0 = *(const bf16x8*)&sK[row*64 + ((( lg    ) ^ (row & 7)) << 3)];
            bf16x8 k1 = *(const bf16x8*)&sK[row*64 + (((lg + 4) ^ (row & 7)) << 3)];
            f32x4 z = {0.f, 0.f, 0.f, 0.f};
            z = MFMA16(qc0, k0, z);
            z = MFMA16(qc1, k1, z);
            sc[nb] = z;
        }

        // ---- P2 band GEMM: the 5 cb blocks this wave needs ----
#pragma unroll
        for (int cbl = 0; cbl < 5; ++cbl) {
            const int cb  = cbl + 7 - w;          // wave-uniform
            const int row = cb*16 + l15;          // sBand row (= dd)
            bf16x8 b0 = *(const bf16x8*)&sBand[row*64 + ((( lg    ) ^ (row & 7)) << 3)];
            bf16x8 b1 = *(const bf16x8*)&sBand[row*64 + (((lg + 4) ^ (row & 7)) << 3)];
            f32x4 z = {0.f, 0.f, 0.f, 0.f};
            if ((dBase + cb*16) >= 1) {
                z = MFMA16(qb0, b0, z);
                z = MFMA16(qb1, b1, z);
            } else {
                z = MFMA16(qa0, b0, z);
                z = MFMA16(qa1, b1, z);
            }
#pragma unroll
            for (int r = 0; r < 4; ++r) {
                const int blm = lg*4 + r;
                const int c = cbl*16 + l15 + blm - 15;
                if ((unsigned)c < 64u) p2w[blm*68 + c] = z[r];
            }
        }
        __builtin_amdgcn_s_setprio(0);
        __asm__ volatile("" ::: "memory");

        // ---- gather shift term ----
        float pm[4];
#pragma unroll
        for (int r = 0; r < 4; ++r) {
            const int blm = lg*4 + r;
            const int blg = w*16 + blm;
#pragma unroll
            for (int nb = 0; nb < 4; ++nb) {
                const int jl = nb*16 + l15;
                const int d  = dBase + jl - blg + 127;
                const float pv = p2w[blm*68 + jl];
                sc[nb][r] += (d == 1) ? 0.f : pv;
            }
            pm[r] = fmaxf(fmaxf(sc[0][r], sc[1][r]), fmaxf(sc[2][r], sc[3][r]));
        }

        // ---- softmax: defer-max fast path ----
        const float over = fmaxf(fmaxf(pm[0]-mrow[0], pm[1]-mrow[1]),
                                 fmaxf(pm[2]-mrow[2], pm[3]-mrow[3]));
        if (__all(over <= 8.0f)) {
#pragma unroll
            for (int r = 0; r < 4; ++r) {
                float p0 = __expf(sc[0][r] - mrow[r]);
                float p1 = __expf(sc[1][r] - mrow[r]);
                float p2 = __expf(sc[2][r] - mrow[r]);
                float p3 = __expf(sc[3][r] - mrow[r]);
                sc[0][r] = p0; sc[1][r] = p1; sc[2][r] = p2; sc[3][r] = p3;
                lsum[r] += p0 + p1 + p2 + p3;
            }
        } else {
            float fsc[4];
#pragma unroll
            for (int r = 0; r < 4; ++r) {
                float mx = pm[r];
                mx = fmaxf(mx, __shfl_xor(mx, 1, 64));
                mx = fmaxf(mx, __shfl_xor(mx, 2, 64));
                mx = fmaxf(mx, __shfl_xor(mx, 4, 64));
                mx = fmaxf(mx, __shfl_xor(mx, 8, 64));
                const float mnew = fmaxf(mrow[r], mx);
                const float fac  = __expf(mrow[r] - mnew);
                mrow[r] = mnew;
                float p0 = __expf(sc[0][r] - mnew);
                float p1 = __expf(sc[1][r] - mnew);
                float p2 = __expf(sc[2][r] - mnew);
                float p3 = __expf(sc[3][r] - mnew);
                sc[0][r] = p0; sc[1][r] = p1; sc[2][r] = p2; sc[3][r] = p3;
                lsum[r] = lsum[r] * fac + (p0 + p1 + p2 + p3);
                fsc[r] = fac;
            }
#pragma unroll
            for (int nb = 0; nb < 4; ++nb)
#pragma unroll
                for (int r = 0; r < 4; ++r)
                    oacc[nb][r] *= fsc[r];
        }
        __asm__ volatile("" ::: "memory");

        // ---- write P (bf16, swizzled; aliases P2 strip; wave-private) ----
#pragma unroll
        for (int r = 0; r < 4; ++r) {
            const int blm = lg*4 + r;
#pragma unroll
            for (int nb = 0; nb < 4; ++nb) {
                const int jl = nb*16 + l15;
                spw[blm*64 + (((jl >> 3) ^ (blm & 7)) << 3) + (jl & 7)] = f2bf(sc[nb][r]);
            }
        }
        __asm__ volatile("" ::: "memory");

        // ---- PV (V from LDS) ----
        __builtin_amdgcn_s_setprio(1);
        {
            bf16x8 pa0 = *(const bf16x8*)&spw[l15*64 + ((( lg    ) ^ (l15 & 7)) << 3)];
            bf16x8 pa1 = *(const bf16x8*)&spw[l15*64 + (((lg + 4) ^ (l15 & 7)) << 3)];
#pragma unroll
            for (int nb = 0; nb < 4; ++nb) {
                const int row = nb*16 + l15;
                bf16x8 v0 = *(const bf16x8*)&sV[row*64 + ((( lg    ) ^ (row & 7)) << 3)];
                bf16x8 v1 = *(const bf16x8*)&sV[row*64 + (((lg + 4) ^ (row & 7)) << 3)];
                oacc[nb] = MFMA16(pa0, v0, oacc[nb]);
                oacc[nb] = MFMA16(pa1, v1, oacc[nb]);
            }
        }
        __builtin_amdgcn_s_setprio(0);
    }

    // ---- epilogue: reduce l, store bf16 O partial + (m,l) ----
    u16* Op = Opart + (size_t)sp * (Bc*Hc*Lc*DKc) + ho;
#pragma unroll
    for (int r = 0; r < 4; ++r) {
        float ls = lsum[r];
        ls += __shfl_xor(ls, 1, 64);
        ls += __shfl_xor(ls, 2, 64);
        ls += __shfl_xor(ls, 4, 64);
        ls += __shfl_xor(ls, 8, 64);
        const int bl = w*16 + lg*4 + r;
#pragma unroll
        for (int nb = 0; nb < 4; ++nb)
            Op[(size_t)(i0 + bl)*64 + nb*16 + l15] = f2bf(oacc[nb][r]);
        if (l15 == 0) {
            const int rglob = (b*Hc + h)*Lc + i0 + bl;
            *(float2*)&mlbuf[((size_t)sp*BHLc + rglob)*2] = make_float2(mrow[r], ls);
        }
    }
}

// ---------------------------------------------------------------------------
// Combine NSPLIT bf16 partials -> bf16 Oh (in-place into split 0).
// ---------------------------------------------------------------------------
__global__ __launch_bounds__(256)
void attn_combine(const u16* __restrict__ Opart, const float* __restrict__ mlbuf,
                  u16* __restrict__ Oh)
{
    const int t = threadIdx.x;
    const int row = blockIdx.x * 64 + (t >> 2);
    const int q = t & 3;
    const size_t NQl = (size_t)Bc * Hc * Lc * DKc;

    float m[NSPLIT], l[NSPLIT];
#pragma unroll
    for (int s = 0; s < NSPLIT; ++s) {
        float2 ml = *(const float2*)&mlbuf[((size_t)s*BHLc + row)*2];
        m[s] = ml.x; l[s] = ml.y;
    }
    float M = fmaxf(fmaxf(m[0], m[1]), fmaxf(m[2], m[3]));
    float wgt[NSPLIT], wsum = 0.f;
#pragma unroll
    for (int s = 0; s < NSPLIT; ++s) { wgt[s] = __expf(m[s] - M); wsum += l[s]*wgt[s]; }
    const float inv = 1.f / wsum;

    float acc[16] = {};
#pragma unroll
    for (int s = 0; s < NSPLIT; ++s) {
        const i32x4* src = (const i32x4*)(Opart + (size_t)s*NQl + (size_t)row*64 + q*16);
        U16x8 a, bb; a.v = src[0]; bb.v = src[1];
#pragma unroll
        for (int e = 0; e < 8; ++e) {
            acc[e]   += wgt[s] * bf2f(a.us[e]);
            acc[8+e] += wgt[s] * bf2f(bb.us[e]);
        }
    }
    U16x8 o0, o1;
#pragma unroll
    for (int e = 0; e < 8; ++e) {
        o0.us[e] = f2bf(acc[e]   * inv);
        o1.us[e] = f2bf(acc[8+e] * inv);
    }
    i32x4* dst = (i32x4*)(Oh + (size_t)row*64 + q*16);
    dst[0] = o0.v; dst[1] = o1.v;
}

// ---------------------------------------------------------------------------
// LayerNorm (unchanged)
// ---------------------------------------------------------------------------
__global__ __launch_bounds__(256)
void ln_kernel(const float* __restrict__ yr, const float* __restrict__ g,
               const float* __restrict__ be, float* __restrict__ out)
{
    const int row = blockIdx.x;
    const int t   = threadIdx.x;
    const float2 v = *(const float2*)&yr[(size_t)row * 512 + t*2];
    float sum = v.x + v.y;
    float sq  = v.x*v.x + v.y*v.y;
#pragma unroll
    for (int off = 1; off < 64; off <<= 1) {
        sum += __shfl_xor(sum, off, 64);
        sq  += __shfl_xor(sq,  off, 64);
    }
    __shared__ float ssum[4], ssq[4];
    if ((t & 63) == 0) { ssum[t >> 6] = sum; ssq[t >> 6] = sq; }
    __syncthreads();
    sum = ssum[0] + ssum[1] + ssum[2] + ssum[3];
    sq  = ssq[0]  + ssq[1]  + ssq[2]  + ssq[3];
    const float mu   = sum * (1.f / 512.f);
    const float var  = sq * (1.f / 512.f) - mu * mu;
    const float rstd = rsqrtf(var + 1e-5f);
    float2 ov;
    ov.x = (v.x - mu) * rstd * g[t*2+0] + be[t*2+0];
    ov.y = (v.y - mu) * rstd * g[t*2+1] + be[t*2+1];
    *(float2*)&out[(size_t)row * 512 + t*2] = ov;
}

// ---------------------------------------------------------------------------
extern "C" void kernel_launch(void* const* d_in, const int* in_sizes, int n_in,
                              void* d_out, int out_size, void* d_ws, size_t ws_size,
                              hipStream_t stream)
{
    const float* E    = (const float*)d_in[0];
    const float* Ev   = (const float*)d_in[1];
    const float* R    = (const float*)d_in[2];
    const float* Wq   = (const float*)d_in[3];
    const float* Wke  = (const float*)d_in[4];
    const float* Wv   = (const float*)d_in[5];
    const float* Wkr  = (const float*)d_in[6];
    const float* cb   = (const float*)d_in[7];
    const float* pb   = (const float*)d_in[8];
    const float* Wo_w = (const float*)d_in[9];
    const float* Wo_b = (const float*)d_in[10];
    const float* ln_g = (const float*)d_in[11];
    const float* ln_b = (const float*)d_in[12];
    float* out = (float*)d_out;

    const size_t NQ = (size_t)Bc * Hc * Lc * DKc;   // 2,097,152
    const size_t NR = (size_t)Hc * Lc * DKc;        // 1,048,576
    const size_t need = (4*NQ + NR)*2 + (size_t)NSPLIT*NQ*2 + (size_t)NSPLIT*BHLc*2*4;
    if (ws_size < need) return;

    u16* qcB  = (u16*)d_ws;
    u16* qpB  = qcB + NQ;
    u16* kB   = qpB + NQ;
    u16* vtB  = kB  + NQ;
    u16* qrtB = vtB + NQ;
    u16* Opart = qrtB + NR;                         // NSPLIT * NQ u16
    float* mlbuf = (float*)(Opart + (size_t)NSPLIT*NQ);
    u16* Oh16 = Opart;                              // combine output aliases split 0
    float* yr = (float*)(Opart + NQ);               // aliases splits 1-2 (f32 NQ)

    dim3 blk(256);
    // merged pre-GEMMs: qc/qp/k (512 blk) + V^T (512 blk) + QRT (256 blk)
    pre_gemms<<<dim3(1280), blk, 0, stream>>>(E, Wq, Wke, cb, pb, Wv, Ev, R, Wkr,
                                              qcB, qpB, kB, vtB, qrtB);
    // fused MFMA attention, j-split: grid = B*H*NSPLIT*(L/128) = 1024, 512 thr
    attn_mfma<<<dim3(Bc*Hc*NSPLIT*(Lc/128)), dim3(512), 0, stream>>>(qcB, qpB, kB, vtB, qrtB, Opart, mlbuf);
    attn_combine<<<dim3(BHLc/64), blk, 0, stream>>>(Opart, mlbuf, Oh16);
    // y = Ev + Oh(bf16, flat 4096x512) @ Wo_w^T + Wo_b (fp32)
    gemm_mfma<0,1,0,0,1,1,1><<<dim3(64,8), blk, 0, stream>>>((const float*)Oh16, Wo_w, Wo_b, nullptr, Ev, yr, nullptr, 512);
    // layernorm
    ln_kernel<<<dim3(4096), blk, 0, stream>>>(yr, ln_g, ln_b, out);
}

// Round 15
// 159.070 us; speedup vs baseline: 2.3834x; 1.0227x over previous
//
#include <hip/hip_runtime.h>
#include <hip/hip_bf16.h>

// Problem constants
#define Lc   2048
#define Dc   512
#define Hc   8
#define DKc  64
#define Bc   2
#define NSPLIT 4
#define BHLc (Bc*Hc*Lc)

typedef __attribute__((ext_vector_type(8))) short bf16x8;
typedef __attribute__((ext_vector_type(4))) float f32x4;
typedef __attribute__((ext_vector_type(4))) int   i32x4;
typedef unsigned short u16;

#define MFMA16(a, b, c) __builtin_amdgcn_mfma_f32_16x16x32_bf16((a), (b), (c), 0, 0, 0)

__device__ __forceinline__ u16 f2bf(float x) {
    union { float f; unsigned u; } v; v.f = x;
    unsigned r = v.u + 0x7FFFu + ((v.u >> 16) & 1u);   // RNE
    return (u16)(r >> 16);
}
__device__ __forceinline__ float bf2f(u16 x) {
    union { unsigned u; float f; } v; v.u = ((unsigned)x) << 16; return v.f;
}

union U16x8 { u16 us[8]; i32x4 v; };

// ---------------------------------------------------------------------------
// Stage a 64x64 fp32 tile -> bf16 LDS [row][k], XOR-swizzled 16B groups
// ---------------------------------------------------------------------------
template<int TRANS>
__device__ __forceinline__ void stage_tile(u16* sDst, const float* __restrict__ src,
                                           int r0, int k0, int ld, int t)
{
    if (!TRANS) {
        const int row = t >> 2, q = t & 3;
        const float* s = src + (size_t)(r0 + row) * ld + k0 + q * 16;
        float4 f0 = ((const float4*)s)[0];
        float4 f1 = ((const float4*)s)[1];
        float4 f2 = ((const float4*)s)[2];
        float4 f3 = ((const float4*)s)[3];
        U16x8 a, b;
        a.us[0]=f2bf(f0.x); a.us[1]=f2bf(f0.y); a.us[2]=f2bf(f0.z); a.us[3]=f2bf(f0.w);
        a.us[4]=f2bf(f1.x); a.us[5]=f2bf(f1.y); a.us[6]=f2bf(f1.z); a.us[7]=f2bf(f1.w);
        b.us[0]=f2bf(f2.x); b.us[1]=f2bf(f2.y); b.us[2]=f2bf(f2.z); b.us[3]=f2bf(f2.w);
        b.us[4]=f2bf(f3.x); b.us[5]=f2bf(f3.y); b.us[6]=f2bf(f3.z); b.us[7]=f2bf(f3.w);
        const int r7 = row & 7, base = row * 64;
        *(i32x4*)&sDst[base + (((q*2)     ^ r7) << 3)] = a.v;
        *(i32x4*)&sDst[base + (((q*2 + 1) ^ r7) << 3)] = b.v;
    } else {
        const int qq = t & 31, mg = t >> 5;
        const float* s0 = src + (size_t)(k0 + 2*qq) * ld + r0 + mg*8;
        const float* s1 = s0 + ld;
        float4 x0 = ((const float4*)s0)[0], x1 = ((const float4*)s0)[1];
        float4 y0 = ((const float4*)s1)[0], y1 = ((const float4*)s1)[1];
        float e0[8] = {x0.x,x0.y,x0.z,x0.w,x1.x,x1.y,x1.z,x1.w};
        float e1[8] = {y0.x,y0.y,y0.z,y0.w,y1.x,y1.y,y1.z,y1.w};
        unsigned* d32 = (unsigned*)sDst;
        const int g = qq >> 2, off = qq & 3;
#pragma unroll
        for (int e = 0; e < 8; ++e) {
            const int m = mg*8 + e;
            unsigned pk = (unsigned)f2bf(e0[e]) | ((unsigned)f2bf(e1[e]) << 16);
            d32[m*32 + ((g ^ (m & 7)) << 2) + off] = pk;
        }
    }
}

// ---------------------------------------------------------------------------
// GEMM core (device fn; LDS passed in). ABF=1: A already bf16 row-major.
// ---------------------------------------------------------------------------
template<int AT, int WT, int OUTMODE, int DUAL, int HASBIAS, int ADDSRC, int ABF>
__device__ __forceinline__
void gemm_core(u16* sA, u16* sB, int m0, int n0,
               const float* __restrict__ A, const float* __restrict__ W,
               const float* __restrict__ b1, const float* __restrict__ b2,
               const float* __restrict__ add, void* __restrict__ o1v,
               void* __restrict__ o2v, int ldA, int t)
{
    const int lane = t & 63, w = t >> 6;
    const int l15 = lane & 15, lg = lane >> 4;
    const int wm = w >> 1, wn = w & 1;

    f32x4 acc[2][2] = {};

    for (int k0 = 0; k0 < 512; k0 += 64) {
        __syncthreads();
        if (ABF) {
            const u16* A16 = (const u16*)A;
            const int row = t >> 2, q = t & 3;
            const u16* s = A16 + (size_t)(m0 + row) * 512 + k0 + q*16;
            i32x4 v0 = ((const i32x4*)s)[0];
            i32x4 v1 = ((const i32x4*)s)[1];
            const int r7 = row & 7, base = row * 64;
            *(i32x4*)&sA[base + (((q*2)     ^ r7) << 3)] = v0;
            *(i32x4*)&sA[base + (((q*2 + 1) ^ r7) << 3)] = v1;
        } else {
            stage_tile<AT>(sA, A, m0, k0, AT ? ldA : 512, t);
        }
        stage_tile<WT ? 0 : 1>(sB, W, n0, k0, 512, t);
        __syncthreads();
        const int l7 = l15 & 7;
#pragma unroll
        for (int kh = 0; kh < 2; ++kh) {
            bf16x8 av[2], bv[2];
#pragma unroll
            for (int f = 0; f < 2; ++f) {
                const int ra = wm*32 + f*16 + l15;
                av[f] = *(const bf16x8*)&sA[ra*64 + (((kh*4 + lg) ^ l7) << 3)];
                const int rb = wn*32 + f*16 + l15;
                bv[f] = *(const bf16x8*)&sB[rb*64 + (((kh*4 + lg) ^ l7) << 3)];
            }
#pragma unroll
            for (int fm = 0; fm < 2; ++fm)
#pragma unroll
                for (int fn = 0; fn < 2; ++fn)
                    acc[fm][fn] = MFMA16(av[fm], bv[fn], acc[fm][fn]);
        }
    }

#pragma unroll
    for (int fm = 0; fm < 2; ++fm)
#pragma unroll
    for (int fn = 0; fn < 2; ++fn) {
        const int colg = n0 + wn*32 + fn*16 + l15;
#pragma unroll
        for (int r = 0; r < 4; ++r) {
            const int row = m0 + wm*32 + fm*16 + lg*4 + r;
            float v = acc[fm][fn][r];
            if (OUTMODE == 0) {
                if (HASBIAS) v += b1[colg];
                if (ADDSRC)  v += add[(size_t)row*512 + colg];
                ((float*)o1v)[(size_t)row*512 + colg] = v;
            } else if (OUTMODE == 1) {
                if (HASBIAS) v += b1[colg];
                const int h = colg >> 6, dk = colg & 63;
                const int bb = row >> 11, ii = row & 2047;
                const size_t idx = (((size_t)(bb*Hc + h)*Lc + ii) << 6) + dk;
                ((u16*)o1v)[idx] = f2bf(v);
                if (DUAL)
                    ((u16*)o2v)[idx] = f2bf(acc[fm][fn][r] + b2[colg]);
            } else if (OUTMODE == 2) {
                const int h = row >> 6, dk = row & 63;
                const int bb = colg >> 11, ii = colg & 2047;
                ((u16*)o1v)[((size_t)(bb*Hc + h)*DKc + dk)*Lc + ii] = f2bf(v);
            } else {
                const int h = colg >> 6, dk = colg & 63;
                ((u16*)o1v)[(((size_t)h*Lc + row) << 6) + dk] = f2bf(v);
            }
        }
    }
}

// ---------------------------------------------------------------------------
// Tri-output core: qc = E@Wq + cb, qp = E@Wq + pb, k = E@Wke.
// ---------------------------------------------------------------------------
__device__ __forceinline__
void qkp_core(u16* sA, u16* sB1, u16* sB2, int m0, int n0,
              const float* __restrict__ E, const float* __restrict__ Wq,
              const float* __restrict__ Wke, const float* __restrict__ cb,
              const float* __restrict__ pb, u16* __restrict__ qcB,
              u16* __restrict__ qpB, u16* __restrict__ kB, int t)
{
    const int lane = t & 63, w = t >> 6;
    const int l15 = lane & 15, lg = lane >> 4;
    const int wm = w >> 1, wn = w & 1;

    f32x4 acc1[2][2] = {};
    f32x4 acc2[2][2] = {};

    for (int k0 = 0; k0 < 512; k0 += 64) {
        __syncthreads();
        stage_tile<0>(sA,  E,   m0, k0, 512, t);
        stage_tile<1>(sB1, Wq,  n0, k0, 512, t);
        stage_tile<1>(sB2, Wke, n0, k0, 512, t);
        __syncthreads();
        const int l7 = l15 & 7;
#pragma unroll
        for (int kh = 0; kh < 2; ++kh) {
            bf16x8 av[2], b1v[2], b2v[2];
#pragma unroll
            for (int f = 0; f < 2; ++f) {
                const int ra = wm*32 + f*16 + l15;
                av[f]  = *(const bf16x8*)&sA [ra*64 + (((kh*4 + lg) ^ l7) << 3)];
                const int rb = wn*32 + f*16 + l15;
                b1v[f] = *(const bf16x8*)&sB1[rb*64 + (((kh*4 + lg) ^ l7) << 3)];
                b2v[f] = *(const bf16x8*)&sB2[rb*64 + (((kh*4 + lg) ^ l7) << 3)];
            }
#pragma unroll
            for (int fm = 0; fm < 2; ++fm)
#pragma unroll
                for (int fn = 0; fn < 2; ++fn) {
                    acc1[fm][fn] = MFMA16(av[fm], b1v[fn], acc1[fm][fn]);
                    acc2[fm][fn] = MFMA16(av[fm], b2v[fn], acc2[fm][fn]);
                }
        }
    }

#pragma unroll
    for (int fm = 0; fm < 2; ++fm)
#pragma unroll
    for (int fn = 0; fn < 2; ++fn) {
        const int colg = n0 + wn*32 + fn*16 + l15;
        const int h = colg >> 6, dk = colg & 63;
#pragma unroll
        for (int r = 0; r < 4; ++r) {
            const int row = m0 + wm*32 + fm*16 + lg*4 + r;
            const int bb = row >> 11, ii = row & 2047;
            const size_t idx = (((size_t)(bb*Hc + h)*Lc + ii) << 6) + dk;
            qcB[idx] = f2bf(acc1[fm][fn][r] + cb[colg]);
            qpB[idx] = f2bf(acc1[fm][fn][r] + pb[colg]);
            kB[idx]  = f2bf(acc2[fm][fn][r]);
        }
    }
}

// ---------------------------------------------------------------------------
// Merged pre-GEMM dispatch: blocks [0,512) qc/qp/k tri-GEMM,
// [512,1024) V^T, [1024,1280) QRT. One 24KB LDS arena shared by all roles.
// ---------------------------------------------------------------------------
__global__ __launch_bounds__(256)
void pre_gemms(const float* __restrict__ E, const float* __restrict__ Wq,
               const float* __restrict__ Wke, const float* __restrict__ cb,
               const float* __restrict__ pb, const float* __restrict__ Wv,
               const float* __restrict__ Ev, const float* __restrict__ R,
               const float* __restrict__ Wkr,
               u16* __restrict__ qcB, u16* __restrict__ qpB, u16* __restrict__ kB,
               u16* __restrict__ vtB, u16* __restrict__ qrtB)
{
    __shared__ __align__(16) u16 smem[3*64*64];
    const int bid = blockIdx.x;
    const int t = threadIdx.x;
    if (bid < 512) {
        qkp_core(smem, smem + 4096, smem + 8192, (bid & 63) * 64, (bid >> 6) * 64,
                 E, Wq, Wke, cb, pb, qcB, qpB, kB, t);
    } else if (bid < 1024) {
        const int b2 = bid - 512;
        gemm_core<1,1,2,0,0,0,0>(smem, smem + 4096, (b2 & 7) * 64, (b2 >> 3) * 64,
                 Wv, Ev, nullptr, nullptr, nullptr, (void*)vtB, nullptr, 512, t);
    } else {
        const int b3 = bid - 1024;
        gemm_core<1,1,3,0,0,0,0>(smem, smem + 4096, (b3 & 31) * 64, (b3 >> 5) * 64,
                 R, Wkr, nullptr, nullptr, nullptr, (void*)qrtB, nullptr, 2048, t);
    }
}

// ---------------------------------------------------------------------------
// Standalone GEMM wrapper (used for the output projection, ABF path).
// ---------------------------------------------------------------------------
template<int AT, int WT, int OUTMODE, int DUAL, int HASBIAS, int ADDSRC, int ABF = 0>
__global__ __launch_bounds__(256)
void gemm_mfma(const float* __restrict__ A, const float* __restrict__ W,
               const float* __restrict__ b1, const float* __restrict__ b2,
               const float* __restrict__ add, void* __restrict__ o1v,
               void* __restrict__ o2v, int ldA)
{
    __shared__ __align__(16) u16 sA[64*64];
    __shared__ __align__(16) u16 sB[64*64];
    gemm_core<AT,WT,OUTMODE,DUAL,HASBIAS,ADDSRC,ABF>(
        sA, sB, blockIdx.x * 64, blockIdx.y * 64,
        A, W, b1, b2, add, o1v, o2v, ldA, threadIdx.x);
}

// ---------------------------------------------------------------------------
// MFMA fused relative attention, j-split — r10/r12 structure (best measured:
// attn 109.5 us). [79][17] P2 strip, full band staging, defer-max,
// deferred-l, bf16 Opart. LDS 54272 B -> 3 blocks/CU. VGPR 120.
// ---------------------------------------------------------------------------
__global__ __launch_bounds__(256, 4)
void attn_mfma(const u16* __restrict__ qc, const u16* __restrict__ qp,
               const u16* __restrict__ kk, const u16* __restrict__ vt,
               const u16* __restrict__ qrt, u16* __restrict__ Opart,
               float* __restrict__ mlbuf)
{
    __shared__ __align__(16) u16 sK[64*64];
    __shared__ __align__(16) u16 sV[64*64];
    __shared__ __align__(16) u16 sBand[128*64];
    __shared__ __align__(16) float sP2[4*1344];

    const int orig = ((blockIdx.x & 7) << 8) | (blockIdx.x >> 3);
    const int it = orig & 31;
    const int sp = (orig >> 5) & (NSPLIT - 1);
    const int bh = orig >> 7;
    const int h = bh & 7, b = bh >> 3;
    const int i0 = it << 6;
    const int t = threadIdx.x;
    const int lane = t & 63, w = t >> 6;
    const int l15 = lane & 15, lg = lane >> 4;

    float* p2w = sP2 + w * 1344;
    u16*   spw = (u16*)p2w;

    const size_t ho = (size_t)(b*Hc + h) * (Lc * DKc);
    const u16* qcH  = qc  + ho;
    const u16* qpH  = qp  + ho;
    const u16* kH   = kk  + ho;
    const u16* vtH  = vt  + ho;
    const u16* qrtH = qrt + (size_t)h * (Lc * DKc);

    const int rowA = i0 + w*16 + l15;
    const int rowB = (rowA + 1 < Lc) ? rowA + 1 : Lc - 1;
    bf16x8 qc0 = *(const bf16x8*)(qcH + (size_t)rowA*64 +      lg*8);
    bf16x8 qc1 = *(const bf16x8*)(qcH + (size_t)rowA*64 + 32 + lg*8);
    bf16x8 qa0 = *(const bf16x8*)(qpH + (size_t)rowA*64 +      lg*8);
    bf16x8 qa1 = *(const bf16x8*)(qpH + (size_t)rowA*64 + 32 + lg*8);
    bf16x8 qb0 = *(const bf16x8*)(qpH + (size_t)rowB*64 +      lg*8);
    bf16x8 qb1 = *(const bf16x8*)(qpH + (size_t)rowB*64 + 32 + lg*8);

    f32x4 oacc[4] = {};
    float mrow[4] = {-1e30f, -1e30f, -1e30f, -1e30f};
    float lsum[4] = {0.f, 0.f, 0.f, 0.f};

    for (int jq = 0; jq < 32/NSPLIT; ++jq) {
        const int jt = sp * (32/NSPLIT) + jq;
        const int j0 = jt << 6;
        const int dBase = j0 - i0 - 63;
        __syncthreads();
        // ---- stage K, V^T, Band (reg -> swizzled LDS) ----
#pragma unroll
        for (int p = 0; p < 2; ++p) {
            const int s = t + p*256, row = s >> 3, g = s & 7;
            const int sl = row*64 + ((g ^ (row & 7)) << 3);
            *(i32x4*)&sK[sl] = *(const i32x4*)(kH  + (size_t)(j0+row)*64 + g*8);
            *(i32x4*)&sV[sl] = *(const i32x4*)(vtH + (size_t)row*Lc + j0 + g*8);
        }
#pragma unroll
        for (int p = 0; p < 4; ++p) {
            const int s = t + p*256, dd = s >> 3, g = s & 7;
            const int d = dBase + dd;
            const int m = (d <= 0) ? (d + Lc - 1) : ((d >= 2) ? (d - 2) : 0);
            *(i32x4*)&sBand[dd*64 + ((g ^ (dd & 7)) << 3)] =
                *(const i32x4*)(qrtH + (size_t)m*64 + g*8);
        }
        __syncthreads();

        // ---- qk scores ----
        __builtin_amdgcn_s_setprio(1);
        f32x4 sc[4];
#pragma unroll
        for (int nb = 0; nb < 4; ++nb) {
            const int row = nb*16 + l15;
            bf16x8 k0 = *(const bf16x8*)&sK[row*64 + ((( lg    ) ^ (row & 7)) << 3)];
            bf16x8 k1 = *(const bf16x8*)&sK[row*64 + (((lg + 4) ^ (row & 7)) << 3)];
            f32x4 z = {0.f, 0.f, 0.f, 0.f};
            z = MFMA16(qc0, k0, z);
            z = MFMA16(qc1, k1, z);
            sc[nb] = z;
        }

        // ---- P2 band GEMM: only the 5 cb blocks this wave needs ----
#pragma unroll
        for (int cbl = 0; cbl < 5; ++cbl) {
            const int cb  = cbl + 3 - w;
            const int row = cb*16 + l15;
            bf16x8 b0 = *(const bf16x8*)&sBand[row*64 + ((( lg    ) ^ (row & 7)) << 3)];
            bf16x8 b1 = *(const bf16x8*)&sBand[row*64 + (((lg + 4) ^ (row & 7)) << 3)];
            f32x4 z = {0.f, 0.f, 0.f, 0.f};
            if ((dBase + cb*16) >= 1) {
                z = MFMA16(qb0, b0, z);
                z = MFMA16(qb1, b1, z);
            } else {
                z = MFMA16(qa0, b0, z);
                z = MFMA16(qa1, b1, z);
            }
            if (!(cbl == 4 && l15 == 15)) {
                const int base = (cbl*16 + l15)*17 + lg*4;
                p2w[base+0] = z[0]; p2w[base+1] = z[1];
                p2w[base+2] = z[2]; p2w[base+3] = z[3];
            }
        }
        __builtin_amdgcn_s_setprio(0);
        __asm__ volatile("" ::: "memory");

        // ---- gather shift term ----
        float pm[4];
#pragma unroll
        for (int r = 0; r < 4; ++r) {
            const int blm = lg*4 + r;
            const int blg = w*16 + blm;
#pragma unroll
            for (int nb = 0; nb < 4; ++nb) {
                const int jl = nb*16 + l15;
                const int d  = dBase + jl - blg + 63;
                const float pv = p2w[(jl - blm + 15)*17 + blm];
                sc[nb][r] += (d == 1) ? 0.f : pv;
            }
            pm[r] = fmaxf(fmaxf(sc[0][r], sc[1][r]), fmaxf(sc[2][r], sc[3][r]));
        }

        // ---- softmax: defer-max fast path ----
        const float over = fmaxf(fmaxf(pm[0]-mrow[0], pm[1]-mrow[1]),
                                 fmaxf(pm[2]-mrow[2], pm[3]-mrow[3]));
        if (__all(over <= 8.0f)) {
#pragma unroll
            for (int r = 0; r < 4; ++r) {
                float p0 = __expf(sc[0][r] - mrow[r]);
                float p1 = __expf(sc[1][r] - mrow[r]);
                float p2 = __expf(sc[2][r] - mrow[r]);
                float p3 = __expf(sc[3][r] - mrow[r]);
                sc[0][r] = p0; sc[1][r] = p1; sc[2][r] = p2; sc[3][r] = p3;
                lsum[r] += p0 + p1 + p2 + p3;
            }
        } else {
            float fsc[4];
#pragma unroll
            for (int r = 0; r < 4; ++r) {
                float mx = pm[r];
                mx = fmaxf(mx, __shfl_xor(mx, 1, 64));
                mx = fmaxf(mx, __shfl_xor(mx, 2, 64));
                mx = fmaxf(mx, __shfl_xor(mx, 4, 64));
                mx = fmaxf(mx, __shfl_xor(mx, 8, 64));
                const float mnew = fmaxf(mrow[r], mx);
                const float fac  = __expf(mrow[r] - mnew);
                mrow[r] = mnew;
                float p0 = __expf(sc[0][r] - mnew);
                float p1 = __expf(sc[1][r] - mnew);
                float p2 = __expf(sc[2][r] - mnew);
                float p3 = __expf(sc[3][r] - mnew);
                sc[0][r] = p0; sc[1][r] = p1; sc[2][r] = p2; sc[3][r] = p3;
                lsum[r] = lsum[r] * fac + (p0 + p1 + p2 + p3);
                fsc[r] = fac;
            }
#pragma unroll
            for (int nb = 0; nb < 4; ++nb)
#pragma unroll
                for (int r = 0; r < 4; ++r)
                    oacc[nb][r] *= fsc[r];
        }
        __asm__ volatile("" ::: "memory");

        // ---- write P (bf16, swizzled; aliases P2 strip; wave-private) ----
#pragma unroll
        for (int r = 0; r < 4; ++r) {
            const int blm = lg*4 + r;
#pragma unroll
            for (int nb = 0; nb < 4; ++nb) {
                const int jl = nb*16 + l15;
                spw[blm*64 + (((jl >> 3) ^ (blm & 7)) << 3) + (jl & 7)] = f2bf(sc[nb][r]);
            }
        }
        __asm__ volatile("" ::: "memory");

        // ---- PV (V from LDS) ----
        __builtin_amdgcn_s_setprio(1);
        {
            bf16x8 pa0 = *(const bf16x8*)&spw[l15*64 + ((( lg    ) ^ (l15 & 7)) << 3)];
            bf16x8 pa1 = *(const bf16x8*)&spw[l15*64 + (((lg + 4) ^ (l15 & 7)) << 3)];
#pragma unroll
            for (int nb = 0; nb < 4; ++nb) {
                const int row = nb*16 + l15;
                bf16x8 v0 = *(const bf16x8*)&sV[row*64 + ((( lg    ) ^ (row & 7)) << 3)];
                bf16x8 v1 = *(const bf16x8*)&sV[row*64 + (((lg + 4) ^ (row & 7)) << 3)];
                oacc[nb] = MFMA16(pa0, v0, oacc[nb]);
                oacc[nb] = MFMA16(pa1, v1, oacc[nb]);
            }
        }
        __builtin_amdgcn_s_setprio(0);
    }

    // ---- epilogue: reduce l, store bf16 O partial + (m,l) ----
    u16* Op = Opart + (size_t)sp * (Bc*Hc*Lc*DKc) + ho;
#pragma unroll
    for (int r = 0; r < 4; ++r) {
        float ls = lsum[r];
        ls += __shfl_xor(ls, 1, 64);
        ls += __shfl_xor(ls, 2, 64);
        ls += __shfl_xor(ls, 4, 64);
        ls += __shfl_xor(ls, 8, 64);
        const int bl = w*16 + lg*4 + r;
#pragma unroll
        for (int nb = 0; nb < 4; ++nb)
            Op[(size_t)(i0 + bl)*64 + nb*16 + l15] = f2bf(oacc[nb][r]);
        if (l15 == 0) {
            const int rglob = (b*Hc + h)*Lc + i0 + bl;
            *(float2*)&mlbuf[((size_t)sp*BHLc + rglob)*2] = make_float2(mrow[r], ls);
        }
    }
}

// ---------------------------------------------------------------------------
// Combine NSPLIT bf16 partials -> bf16 Oh (in-place into split 0).
// ---------------------------------------------------------------------------
__global__ __launch_bounds__(256)
void attn_combine(const u16* __restrict__ Opart, const float* __restrict__ mlbuf,
                  u16* __restrict__ Oh)
{
    const int t = threadIdx.x;
    const int row = blockIdx.x * 64 + (t >> 2);
    const int q = t & 3;
    const size_t NQl = (size_t)Bc * Hc * Lc * DKc;

    float m[NSPLIT], l[NSPLIT];
#pragma unroll
    for (int s = 0; s < NSPLIT; ++s) {
        float2 ml = *(const float2*)&mlbuf[((size_t)s*BHLc + row)*2];
        m[s] = ml.x; l[s] = ml.y;
    }
    float M = fmaxf(fmaxf(m[0], m[1]), fmaxf(m[2], m[3]));
    float wgt[NSPLIT], wsum = 0.f;
#pragma unroll
    for (int s = 0; s < NSPLIT; ++s) { wgt[s] = __expf(m[s] - M); wsum += l[s]*wgt[s]; }
    const float inv = 1.f / wsum;

    float acc[16] = {};
#pragma unroll
    for (int s = 0; s < NSPLIT; ++s) {
        const i32x4* src = (const i32x4*)(Opart + (size_t)s*NQl + (size_t)row*64 + q*16);
        U16x8 a, bb; a.v = src[0]; bb.v = src[1];
#pragma unroll
        for (int e = 0; e < 8; ++e) {
            acc[e]   += wgt[s] * bf2f(a.us[e]);
            acc[8+e] += wgt[s] * bf2f(bb.us[e]);
        }
    }
    U16x8 o0, o1;
#pragma unroll
    for (int e = 0; e < 8; ++e) {
        o0.us[e] = f2bf(acc[e]   * inv);
        o1.us[e] = f2bf(acc[8+e] * inv);
    }
    i32x4* dst = (i32x4*)(Oh + (size_t)row*64 + q*16);
    dst[0] = o0.v; dst[1] = o1.v;
}

// ---------------------------------------------------------------------------
// LayerNorm (unchanged)
// ---------------------------------------------------------------------------
__global__ __launch_bounds__(256)
void ln_kernel(const float* __restrict__ yr, const float* __restrict__ g,
               const float* __restrict__ be, float* __restrict__ out)
{
    const int row = blockIdx.x;
    const int t   = threadIdx.x;
    const float2 v = *(const float2*)&yr[(size_t)row * 512 + t*2];
    float sum = v.x + v.y;
    float sq  = v.x*v.x + v.y*v.y;
#pragma unroll
    for (int off = 1; off < 64; off <<= 1) {
        sum += __shfl_xor(sum, off, 64);
        sq  += __shfl_xor(sq,  off, 64);
    }
    __shared__ float ssum[4], ssq[4];
    if ((t & 63) == 0) { ssum[t >> 6] = sum; ssq[t >> 6] = sq; }
    __syncthreads();
    sum = ssum[0] + ssum[1] + ssum[2] + ssum[3];
    sq  = ssq[0]  + ssq[1]  + ssq[2]  + ssq[3];
    const float mu   = sum * (1.f / 512.f);
    const float var  = sq * (1.f / 512.f) - mu * mu;
    const float rstd = rsqrtf(var + 1e-5f);
    float2 ov;
    ov.x = (v.x - mu) * rstd * g[t*2+0] + be[t*2+0];
    ov.y = (v.y - mu) * rstd * g[t*2+1] + be[t*2+1];
    *(float2*)&out[(size_t)row * 512 + t*2] = ov;
}

// ---------------------------------------------------------------------------
extern "C" void kernel_launch(void* const* d_in, const int* in_sizes, int n_in,
                              void* d_out, int out_size, void* d_ws, size_t ws_size,
                              hipStream_t stream)
{
    const float* E    = (const float*)d_in[0];
    const float* Ev   = (const float*)d_in[1];
    const float* R    = (const float*)d_in[2];
    const float* Wq   = (const float*)d_in[3];
    const float* Wke  = (const float*)d_in[4];
    const float* Wv   = (const float*)d_in[5];
    const float* Wkr  = (const float*)d_in[6];
    const float* cb   = (const float*)d_in[7];
    const float* pb   = (const float*)d_in[8];
    const float* Wo_w = (const float*)d_in[9];
    const float* Wo_b = (const float*)d_in[10];
    const float* ln_g = (const float*)d_in[11];
    const float* ln_b = (const float*)d_in[12];
    float* out = (float*)d_out;

    const size_t NQ = (size_t)Bc * Hc * Lc * DKc;   // 2,097,152
    const size_t NR = (size_t)Hc * Lc * DKc;        // 1,048,576
    const size_t need = (4*NQ + NR)*2 + (size_t)NSPLIT*NQ*2 + (size_t)NSPLIT*BHLc*2*4;
    if (ws_size < need) return;

    u16* qcB  = (u16*)d_ws;
    u16* qpB  = qcB + NQ;
    u16* kB   = qpB + NQ;
    u16* vtB  = kB  + NQ;
    u16* qrtB = vtB + NQ;
    u16* Opart = qrtB + NR;                         // NSPLIT * NQ u16
    float* mlbuf = (float*)(Opart + (size_t)NSPLIT*NQ);
    u16* Oh16 = Opart;                              // combine output aliases split 0
    float* yr = (float*)(Opart + NQ);               // aliases splits 1-2 (f32 NQ)

    dim3 blk(256);
    // merged pre-GEMMs: qc/qp/k (512 blk) + V^T (512 blk) + QRT (256 blk)
    pre_gemms<<<dim3(1280), blk, 0, stream>>>(E, Wq, Wke, cb, pb, Wv, Ev, R, Wkr,
                                              qcB, qpB, kB, vtB, qrtB);
    // fused MFMA attention, j-split: grid = B*H*NSPLIT*32 = 2048
    attn_mfma<<<dim3(Bc*Hc*NSPLIT*32), blk, 0, stream>>>(qcB, qpB, kB, vtB, qrtB, Opart, mlbuf);
    attn_combine<<<dim3(BHLc/64), blk, 0, stream>>>(Opart, mlbuf, Oh16);
    // y = Ev + Oh(bf16, flat 4096x512) @ Wo_w^T + Wo_b (fp32)
    gemm_mfma<0,1,0,0,1,1,1><<<dim3(64,8), blk, 0, stream>>>((const float*)Oh16, Wo_w, Wo_b, nullptr, Ev, yr, nullptr, 512);
    // layernorm
    ln_kernel<<<dim3(4096), blk, 0, stream>>>(yr, ln_g, ln_b, out);
}